// Round 7
// baseline (417.741 us; speedup 1.0000x reference)
//
#include <hip/hip_runtime.h>

#define SQ 2048
#define BB 2
#define EE 1024
#define HH 16
#define DD 64
#define MM (SQ*BB)          // 4096 composite rows (s*B + b)
#define NSLICE 4
#define KSLICE (SQ/NSLICE)  // 512 k per attn_main wg
#define KT_IN (KSLICE/128)  // 4 kt tiles of 128
#define LOG2E 1.44269504f

typedef _Float16 f16;
typedef _Float16 half8 __attribute__((ext_vector_type(8)));
typedef _Float16 half4 __attribute__((ext_vector_type(4)));
typedef float f32x4 __attribute__((ext_vector_type(4)));

static __device__ __forceinline__ f32x4 mfma16(half8 a, half8 b, f32x4 c) {
    return __builtin_amdgcn_mfma_f32_16x16x32_f16(a, b, c, 0, 0, 0);
}
static __device__ __forceinline__ f32x4 mfma16k16(half4 a, half4 b, f32x4 c) {
    return __builtin_amdgcn_mfma_f32_16x16x16f16(a, b, c, 0, 0, 0);
}

// async global->LDS, 16B per lane (GEMM staging only)
static __device__ __forceinline__ void gload16(const f16* g, f16* l) {
    __builtin_amdgcn_global_load_lds(
        (const __attribute__((address_space(1))) unsigned int*)g,
        (__attribute__((address_space(3))) unsigned int*)l, 16, 0, 0);
}

// ---------------- fused elementwise converts ----------------
__global__ void k_elem(const float* __restrict__ q_w, const float* __restrict__ k_w,
                       const float* __restrict__ v_w, const float* __restrict__ query,
                       const float* __restrict__ key, const float* __restrict__ value,
                       const float* __restrict__ owm, const float* __restrict__ owl,
                       const float* __restrict__ eps,
                       f16* qw16, f16* kw16, f16* vw16,
                       f16* xq16, f16* xk16, f16* xv16, f16* ow16)
{
    int y = blockIdx.y;
    size_t i = ((size_t)blockIdx.x * 256 + threadIdx.x) * 4;
    if (y < 3) {
        if (i >= (size_t)EE*EE) return;
        const float* s = (y==0) ? q_w : (y==1) ? k_w : v_w;
        f16* d = (y==0) ? qw16 : (y==1) ? kw16 : vw16;
        float4 v = *(const float4*)&s[i];
        half4 o = {(f16)v.x, (f16)v.y, (f16)v.z, (f16)v.w};
        *(half4*)&d[i] = o;
    } else if (y < 6) {
        const float* s = (y==3) ? query : (y==4) ? key : value;
        f16* d = (y==3) ? xq16 : (y==4) ? xk16 : xv16;
        float4 v = *(const float4*)&s[i];
        half4 o = {(f16)v.x, (f16)v.y, (f16)v.z, (f16)v.w};
        *(half4*)&d[i] = o;
    } else {
        if (i >= (size_t)EE*EE) return;
        float4 m = *(const float4*)&owm[i];
        float4 l = *(const float4*)&owl[i];
        float4 e = *(const float4*)&eps[i];
        half4 o = {(f16)(m.x + e.x * __expf(l.x)), (f16)(m.y + e.y * __expf(l.y)),
                   (f16)(m.z + e.z * __expf(l.z)), (f16)(m.w + e.w * __expf(l.w))};
        *(half4*)&ow16[i] = o;
    }
}

// ---------------- GEMM body: C[M,N] = (A[M,K] @ W[N,K]^T + bias) * scale ----------------
// 128x64 tile, BK=32.
// mode 0: f16 -> [b][h][s][d]            (attention-coalesced Q/K)
// mode 1: f16 -> [b][h][s/32][d][32]     (attention-coalesced V^T, k-tiled)
// mode 2: f32 row-major [m][col]
__device__ __forceinline__ void gemm_body(
    const f16* __restrict__ A, const f16* __restrict__ W,
    const float* __restrict__ bias, float scale, void* __restrict__ out, int mode)
{
    __shared__ f16 As[128*32];
    __shared__ f16 Bs[64*32];
    int t = threadIdx.x, lane = t & 63, w = t >> 6;
    int quad = lane >> 4, m16 = lane & 15;
    int wm = w >> 1, wn = w & 1;
    int gm0 = blockIdx.x * 128, gn0 = blockIdx.y * 64;
    int arow = lane >> 2, apch = lane & 3;
    f32x4 acc[4][2] = {};
    for (int kt = 0; kt < EE; kt += 32) {
        #pragma unroll
        for (int j = 0; j < 2; ++j) {
            int row = w*32 + j*16 + arow;
            int lch = apch ^ (row & 3);
            gload16(&A[(size_t)(gm0+row)*EE + kt + lch*8], &As[row*32 + apch*8]);
        }
        {
            int row = w*16 + arow;
            int lch = apch ^ (row & 3);
            gload16(&W[(size_t)(gn0+row)*EE + kt + lch*8], &Bs[row*32 + apch*8]);
        }
        __syncthreads();
        int cs = (quad ^ (m16 & 3)) * 8;
        half8 af[4], bf[2];
        #pragma unroll
        for (int i = 0; i < 4; ++i) af[i] = *(half8*)&As[(wm*64 + i*16 + m16)*32 + cs];
        #pragma unroll
        for (int j = 0; j < 2; ++j) bf[j] = *(half8*)&Bs[(wn*32 + j*16 + m16)*32 + cs];
        #pragma unroll
        for (int i = 0; i < 4; ++i)
            #pragma unroll
            for (int j = 0; j < 2; ++j)
                acc[i][j] = mfma16(af[i], bf[j], acc[i][j]);
        __syncthreads();
    }
    #pragma unroll
    for (int j = 0; j < 2; ++j) {
        int col = gn0 + wn*32 + j*16 + m16;
        int h = col >> 6, d = col & 63;
        float bb = bias ? bias[col] : 0.0f;
        #pragma unroll
        for (int i = 0; i < 4; ++i) {
            int r0 = gm0 + wm*64 + i*16 + quad*4;
            #pragma unroll
            for (int r = 0; r < 4; ++r) {
                float v = (acc[i][j][r] + bb) * scale;
                int m = r0 + r;
                int s = m >> 1, b = m & 1;
                if (mode == 2)
                    ((float*)out)[(size_t)m*EE + col] = v;
                else if (mode == 1)
                    ((f16*)out)[((((size_t)b*HH + h)*(SQ/32) + (s >> 5))*DD + d)*32 + (s & 31)] = (f16)v;
                else
                    ((f16*)out)[(((size_t)b*HH + h)*SQ + s)*DD + d] = (f16)v;
            }
        }
    }
}

__global__ __launch_bounds__(256) void k_gemm_qkv(
    const f16* xq, const f16* qw, const float* qb,
    const f16* xk, const f16* kw, const float* kb,
    const f16* xv, const f16* vw, const float* vb,
    f16* Q16, f16* K16, f16* Vt16)
{
    int z = blockIdx.z;
    const f16* A = (z==0) ? xq : (z==1) ? xk : xv;
    const f16* W = (z==0) ? qw : (z==1) ? kw : vw;
    const float* bi = (z==0) ? qb : (z==1) ? kb : vb;
    float sc = (z==0) ? 0.125f * LOG2E : 1.0f;   // fold log2e into Q
    void* o = (z==0) ? (void*)Q16 : (z==1) ? (void*)K16 : (void*)Vt16;
    gemm_body(A, W, bi, sc, o, (z==2) ? 1 : 0);
}

__global__ __launch_bounds__(256) void k_gemm_o(const f16* A, const f16* W, float* out)
{
    gemm_body(A, W, nullptr, 1.0f, out, 2);
}

// ---------------- phase 1: lse2[b,h,q] = log2(sum_k 2^s2) ----------------
// Q16/K16 are [b][h][s][d]: frag loads are dense contiguous spans per wave.
// Flat 1024-wg grid, XCD-swizzled (combo c&7 == XCD).
__global__ __launch_bounds__(256, 4) void k_attn_l(
    const f16* __restrict__ Q16, const f16* __restrict__ K16, float* __restrict__ lse2)
{
    __shared__ float red[4][64];
    const int t = threadIdx.x, lane = t & 63, w = t >> 6;
    const int quad = lane >> 4, m16 = lane & 15;
    const int bid = blockIdx.x;
    const int xcd = bid & 7, r = bid >> 3;       // r in [0,128)
    const int c = ((r & 3) << 3) + xcd;          // (h,b) combo, c&7 == xcd
    const int q0 = (r >> 2) * 64;                // q-tile in [0,32)*64
    const int h = c >> 1, b = c & 1;
    const f16* Qh = Q16 + ((size_t)b*HH + h)*SQ*DD;
    const f16* Kh = K16 + ((size_t)b*HH + h)*SQ*DD;

    half8 bq[4][2];
    #pragma unroll
    for (int nt = 0; nt < 4; ++nt)
        #pragma unroll
        for (int dk = 0; dk < 2; ++dk)
            bq[nt][dk] = *(const half8*)&Qh[(q0 + nt*16 + m16)*DD + dk*32 + quad*8];

    float lsum[4] = {};
    for (int kt = 0; kt < 16; ++kt) {
        half8 ak[2][2];
        #pragma unroll
        for (int mt = 0; mt < 2; ++mt)
            #pragma unroll
            for (int dk = 0; dk < 2; ++dk)
                ak[mt][dk] = *(const half8*)&Kh[(kt*128 + w*32 + mt*16 + m16)*DD + dk*32 + quad*8];
        #pragma unroll
        for (int mt = 0; mt < 2; ++mt)
            #pragma unroll
            for (int nt = 0; nt < 4; ++nt) {
                f32x4 s = {};
                s = mfma16(ak[mt][0], bq[nt][0], s);   // S^T: rows k, cols q
                s = mfma16(ak[mt][1], bq[nt][1], s);
                lsum[nt] += __builtin_amdgcn_exp2f(s[0]) + __builtin_amdgcn_exp2f(s[1])
                          + __builtin_amdgcn_exp2f(s[2]) + __builtin_amdgcn_exp2f(s[3]);
            }
    }
    #pragma unroll
    for (int nt = 0; nt < 4; ++nt) {
        float v = lsum[nt];
        v += __shfl_xor(v, 16, 64);
        v += __shfl_xor(v, 32, 64);
        lsum[nt] = v;
    }
    if (quad == 0)
        #pragma unroll
        for (int nt = 0; nt < 4; ++nt) red[w][nt*16 + m16] = lsum[nt];
    __syncthreads();
    if (t < 64) {
        float v = red[0][t] + red[1][t] + red[2][t] + red[3][t];
        lse2[((size_t)b*HH + h)*SQ + q0 + t] = __log2f(v);
    }
}

// ---------------- phase 2: probs, avg_attn (regs), ctx partials ----------------
// Flat 512-wg grid, XCD-swizzled ((sl,b) group == XCD, K/V slice L2-resident).
// KEY CHANGE vs prior: NO LDS P-exchange, NO in-loop barriers. The QK S^T
// accumulator layout (lane: P[q=lane&15][k=quad*4+r]) IS the A-operand layout
// of mfma_f32_16x16x16_f16 (lane: A[row=lane&15][k=quad*4+j]) -- so after exp
// the P fragment feeds PV directly in-lane. Each wave covers its own 32-k
// slice for ALL d (4 d-blocks of 16); waves run fully independently through
// the kt loop. Cross-wave ctx reduction happens ONCE per head via LDS
// (2 barriers/head = 32 total, vs 128 lock-step barriers before).
__global__ __launch_bounds__(256, 2) void k_attn_main(
    const f16* __restrict__ Q16, const f16* __restrict__ K16, const f16* __restrict__ Vt16,
    const float* __restrict__ lse2, float* __restrict__ ctxp, float* __restrict__ avg_out)
{
    __shared__ float red[4][3][16][36];   // [dest d-block][src slot][d-local][q padded]
    __shared__ float csh[HH][32];
    const int t = threadIdx.x, lane = t & 63, w = t >> 6;
    const int quad = lane >> 4, m16 = lane & 15;
    const int bid = blockIdx.x;
    const int g = bid & 7;                 // (sl,b) group == XCD
    const int q0 = (bid >> 3) * 32;        // q-tile in [0,64)*32
    const int sl = g >> 1, b = g & 1;
    const int ks0 = sl * KSLICE;

    for (int i = t; i < HH*32; i += 256) {
        int hh = i >> 5, qq = i & 31;
        csh[hh][qq] = lse2[((size_t)b*HH + hh)*SQ + q0 + qq];
    }
    __syncthreads();

    float avg_r[KT_IN][16] = {};   // lane-exclusive (q,k) slots, accumulated over h

    for (int h = 0; h < HH; ++h) {
        const f16* Qh = Q16 + ((size_t)b*HH + h)*SQ*DD;
        const f16* Kh = K16 + ((size_t)b*HH + h)*SQ*DD;
        const f16* Vh = Vt16 + ((size_t)b*HH + h)*(SQ/32)*DD*32;
        half8 bq[2][2];
        #pragma unroll
        for (int nt = 0; nt < 2; ++nt)
            #pragma unroll
            for (int dk = 0; dk < 2; ++dk)
                bq[nt][dk] = *(const half8*)&Qh[(q0 + nt*16 + m16)*DD + dk*32 + quad*8];
        const float c01[2] = { csh[h][m16], csh[h][16 + m16] };

        f32x4 acc[2][4] = {};      // [qt][d-block] ctx partial over this wave's k-slice

        half8 ak[2][2][2];         // [buf][mt][dk] K fragments (double-buffered)
        #pragma unroll
        for (int mt = 0; mt < 2; ++mt)
            #pragma unroll
            for (int dk = 0; dk < 2; ++dk)
                ak[0][mt][dk] = *(const half8*)&Kh[(ks0 + w*32 + mt*16 + m16)*DD + dk*32 + quad*8];

        #pragma unroll
        for (int kt = 0; kt < KT_IN; ++kt) {
            const int cur = kt & 1, nxt = cur ^ 1;
            const int ktile32 = (ks0 + kt*128 + w*32) >> 5;   // 32-k tile index in Vh

            // V fragments for this round: [mt][db], half4 per lane (B of 16x16x16)
            half4 bv[2][4];
            #pragma unroll
            for (int mt = 0; mt < 2; ++mt)
                #pragma unroll
                for (int db = 0; db < 4; ++db)
                    bv[mt][db] = *(const half4*)&Vh[((size_t)ktile32*DD + db*16 + m16)*32 + mt*16 + quad*4];

            if (kt + 1 < KT_IN) {   // prefetch next K tile
                #pragma unroll
                for (int mt = 0; mt < 2; ++mt)
                    #pragma unroll
                    for (int dk = 0; dk < 2; ++dk)
                        ak[nxt][mt][dk] = *(const half8*)&Kh[(ks0 + (kt+1)*128 + w*32 + mt*16 + m16)*DD + dk*32 + quad*8];
            }

            // QK: S^T = K.Q^T; exp in-lane -> P fragments (A of 16x16x16)
            half4 pa[2][2];   // [mt][nt]
            #pragma unroll
            for (int mt = 0; mt < 2; ++mt)
                #pragma unroll
                for (int nt = 0; nt < 2; ++nt) {
                    f32x4 s = {};
                    s = mfma16(ak[cur][mt][0], bq[nt][0], s);
                    s = mfma16(ak[cur][mt][1], bq[nt][1], s);
                    half4 ph;
                    #pragma unroll
                    for (int r = 0; r < 4; ++r) {
                        float p = __builtin_amdgcn_exp2f(s[r] - c01[nt]);
                        avg_r[kt][mt*8 + nt*4 + r] += p;
                        ph[r] = (f16)p;
                    }
                    pa[mt][nt] = ph;
                }

            // PV in-lane: ctx[32q x 64d] partial for this wave's 32 k
            #pragma unroll
            for (int nt = 0; nt < 2; ++nt)
                #pragma unroll
                for (int db = 0; db < 4; ++db) {
                    f32x4 c4 = acc[nt][db];
                    c4 = mfma16k16(pa[0][nt], bv[0][db], c4);
                    c4 = mfma16k16(pa[1][nt], bv[1][db], c4);
                    acc[nt][db] = c4;
                }
        }

        // cross-wave ctx reduce: wave w finalizes d-block w for this head
        #pragma unroll
        for (int db = 0; db < 4; ++db)
            if (db != w) {
                int slot = w - (w > db);
                #pragma unroll
                for (int qt = 0; qt < 2; ++qt)
                    *(f32x4*)&red[db][slot][m16][qt*16 + quad*4] = acc[qt][db];
            }
        __syncthreads();
        #pragma unroll
        for (int qt = 0; qt < 2; ++qt) {
            f32x4 c = acc[qt][w];
            #pragma unroll
            for (int slot = 0; slot < 3; ++slot)
                c = c + *(const f32x4*)&red[w][slot][m16][qt*16 + quad*4];
            #pragma unroll
            for (int r = 0; r < 4; ++r) {
                int q = q0 + qt*16 + quad*4 + r;
                ctxp[(size_t)sl*MM*EE + ((size_t)q*BB + b)*EE + h*DD + w*16 + m16] = c[r];
            }
        }
        __syncthreads();   // red reusable for next head
    }

    // write owned avg tile (float4 stores)
    #pragma unroll
    for (int kt = 0; kt < KT_IN; ++kt)
        #pragma unroll
        for (int mt = 0; mt < 2; ++mt)
            #pragma unroll
            for (int nt = 0; nt < 2; ++nt) {
                int q = q0 + nt*16 + m16;
                int k = ks0 + kt*128 + w*32 + mt*16 + quad*4;
                float4 v = { avg_r[kt][mt*8+nt*4+0]*(1.0f/HH), avg_r[kt][mt*8+nt*4+1]*(1.0f/HH),
                             avg_r[kt][mt*8+nt*4+2]*(1.0f/HH), avg_r[kt][mt*8+nt*4+3]*(1.0f/HH) };
                *(float4*)&avg_out[((size_t)b*SQ + q)*SQ + k] = v;
            }
}

// ---------------- ctx partial reduction: fp32 x NSLICE -> f16 ----------------
__global__ void k_ctx_red(const float* __restrict__ ctxp, f16* __restrict__ ctx16) {
    size_t i = ((size_t)blockIdx.x * 256 + threadIdx.x) * 4;
    float4 s = *(const float4*)&ctxp[i];
    #pragma unroll
    for (int sl = 1; sl < NSLICE; ++sl) {
        float4 v = *(const float4*)&ctxp[(size_t)sl*MM*EE + i];
        s.x += v.x; s.y += v.y; s.z += v.z; s.w += v.w;
    }
    half4 o = {(f16)s.x, (f16)s.y, (f16)s.z, (f16)s.w};
    *(half4*)&ctx16[i] = o;
}

// ---------------- launch ----------------
extern "C" void kernel_launch(void* const* d_in, const int* in_sizes, int n_in,
                              void* d_out, int out_size, void* d_ws, size_t ws_size,
                              hipStream_t stream) {
    const float* query    = (const float*)d_in[0];
    const float* key      = (const float*)d_in[1];
    const float* value    = (const float*)d_in[2];
    const float* q_w      = (const float*)d_in[3];
    const float* q_b      = (const float*)d_in[4];
    const float* k_w      = (const float*)d_in[5];
    const float* k_b      = (const float*)d_in[6];
    const float* v_w      = (const float*)d_in[7];
    const float* v_b      = (const float*)d_in[8];
    const float* o_w_mean = (const float*)d_in[9];
    const float* o_w_lgstd= (const float*)d_in[10];
    const float* eps      = (const float*)d_in[11];
    float* out = (float*)d_out;                  // [S,B,E] fp32
    float* avg = out + (size_t)MM * EE;          // [B,S,S] fp32

    const size_t EWN = (size_t)EE*EE;   // 1M
    const size_t XWN = (size_t)MM*EE;   // 4M
    f16* qw16  = (f16*)d_ws;
    f16* kw16  = qw16 + EWN;
    f16* vw16  = kw16 + EWN;
    f16* ow16  = vw16 + EWN;
    f16* Q16   = ow16 + EWN;
    f16* K16   = Q16  + XWN;
    f16* Vt16  = K16  + XWN;
    f16* ctx16 = Vt16 + XWN;
    float* lse2 = (float*)(ctx16 + XWN);             // B*H*S fp32
    f16* xq16  = (f16*)(lse2 + (size_t)BB*HH*SQ);
    f16* xk16  = xq16 + XWN;
    f16* xv16  = xk16 + XWN;
    // ctxp aliases xq/xk/xv (dead after projections) and extends beyond: NSLICE*16MB
    float* ctxp = (float*)xq16;

    k_elem<<<dim3(XWN/1024, 7), 256, 0, stream>>>(q_w, k_w, v_w, query, key, value,
        o_w_mean, o_w_lgstd, eps, qw16, kw16, vw16, xq16, xk16, xv16, ow16);

    k_gemm_qkv<<<dim3(MM/128, EE/64, 3), 256, 0, stream>>>(
        xq16, qw16, q_b, xk16, kw16, k_b, xv16, vw16, v_b, Q16, K16, Vt16);

    k_attn_l   <<<dim3(SQ/64 * HH * BB), 256, 0, stream>>>(Q16, K16, lse2);
    k_attn_main<<<dim3(SQ/32 * NSLICE * BB), 256, 0, stream>>>(Q16, K16, Vt16, lse2, ctxp, avg);
    k_ctx_red  <<<XWN/1024, 256, 0, stream>>>(ctxp, ctx16);

    k_gemm_o<<<dim3(MM/128, EE/64), 256, 0, stream>>>(ctx16, ow16, out);
}

// Round 8
// 333.450 us; speedup vs baseline: 1.2528x; 1.2528x over previous
//
#include <hip/hip_runtime.h>

#define SQ 2048
#define BB 2
#define EE 1024
#define HH 16
#define DD 64
#define MM (SQ*BB)          // 4096 composite rows (s*B + b)
#define QT 128              // q-tile per attn_main wg
#define NSLICE 16
#define KSLICE (SQ/NSLICE)  // 128 k per attn_main wg
#define LOG2E 1.44269504f

typedef _Float16 f16;
typedef _Float16 half8 __attribute__((ext_vector_type(8)));
typedef _Float16 half4 __attribute__((ext_vector_type(4)));
typedef float f32x4 __attribute__((ext_vector_type(4)));

static __device__ __forceinline__ f32x4 mfma16(half8 a, half8 b, f32x4 c) {
    return __builtin_amdgcn_mfma_f32_16x16x32_f16(a, b, c, 0, 0, 0);
}

// async global->LDS, 16B per lane (GEMM staging only)
static __device__ __forceinline__ void gload16(const f16* g, f16* l) {
    __builtin_amdgcn_global_load_lds(
        (const __attribute__((address_space(1))) unsigned int*)g,
        (__attribute__((address_space(3))) unsigned int*)l, 16, 0, 0);
}

// Q/K fragment-tiled layout: element (bh, s, d) lives at
//   ((bh*(SQ/16) + (s>>4))*2 + (d>>5))*512 + (s&15)*32 + (d&31)
// so one MFMA fragment load (16 s x 32 d) = one contiguous 1KB wave transaction.
static __device__ __forceinline__ size_t qk_frag(size_t bh, int s, int d) {
    return ((bh*(SQ/16) + (s >> 4))*2 + (d >> 5))*512 + (size_t)(s & 15)*32 + (d & 31);
}

// ---------------- fused elementwise converts ----------------
__global__ void k_elem(const float* __restrict__ q_w, const float* __restrict__ k_w,
                       const float* __restrict__ v_w, const float* __restrict__ query,
                       const float* __restrict__ key, const float* __restrict__ value,
                       const float* __restrict__ owm, const float* __restrict__ owl,
                       const float* __restrict__ eps,
                       f16* qw16, f16* kw16, f16* vw16,
                       f16* xq16, f16* xk16, f16* xv16, f16* ow16)
{
    int y = blockIdx.y;
    size_t i = ((size_t)blockIdx.x * 256 + threadIdx.x) * 4;
    if (y < 3) {
        if (i >= (size_t)EE*EE) return;
        const float* s = (y==0) ? q_w : (y==1) ? k_w : v_w;
        f16* d = (y==0) ? qw16 : (y==1) ? kw16 : vw16;
        float4 v = *(const float4*)&s[i];
        half4 o = {(f16)v.x, (f16)v.y, (f16)v.z, (f16)v.w};
        *(half4*)&d[i] = o;
    } else if (y < 6) {
        const float* s = (y==3) ? query : (y==4) ? key : value;
        f16* d = (y==3) ? xq16 : (y==4) ? xk16 : xv16;
        float4 v = *(const float4*)&s[i];
        half4 o = {(f16)v.x, (f16)v.y, (f16)v.z, (f16)v.w};
        *(half4*)&d[i] = o;
    } else {
        if (i >= (size_t)EE*EE) return;
        float4 m = *(const float4*)&owm[i];
        float4 l = *(const float4*)&owl[i];
        float4 e = *(const float4*)&eps[i];
        half4 o = {(f16)(m.x + e.x * __expf(l.x)), (f16)(m.y + e.y * __expf(l.y)),
                   (f16)(m.z + e.z * __expf(l.z)), (f16)(m.w + e.w * __expf(l.w))};
        *(half4*)&ow16[i] = o;
    }
}

// ---------------- GEMM body: C[M,N] = (A[M,K] @ W[N,K]^T + bias) * scale ----------------
// 128x64 tile, BK=32.
// mode 0: f16 -> Q/K fragment-tiled (see qk_frag)
// mode 1: f16 -> [b][h][s/32][d][32]     (attention-coalesced V^T, k-tiled)
// mode 2: f32 row-major [m][col]
__device__ __forceinline__ void gemm_body(
    const f16* __restrict__ A, const f16* __restrict__ W,
    const float* __restrict__ bias, float scale, void* __restrict__ out, int mode)
{
    __shared__ f16 As[128*32];
    __shared__ f16 Bs[64*32];
    int t = threadIdx.x, lane = t & 63, w = t >> 6;
    int quad = lane >> 4, m16 = lane & 15;
    int wm = w >> 1, wn = w & 1;
    int gm0 = blockIdx.x * 128, gn0 = blockIdx.y * 64;
    int arow = lane >> 2, apch = lane & 3;
    f32x4 acc[4][2] = {};
    for (int kt = 0; kt < EE; kt += 32) {
        #pragma unroll
        for (int j = 0; j < 2; ++j) {
            int row = w*32 + j*16 + arow;
            int lch = apch ^ (row & 3);
            gload16(&A[(size_t)(gm0+row)*EE + kt + lch*8], &As[row*32 + apch*8]);
        }
        {
            int row = w*16 + arow;
            int lch = apch ^ (row & 3);
            gload16(&W[(size_t)(gn0+row)*EE + kt + lch*8], &Bs[row*32 + apch*8]);
        }
        __syncthreads();
        int cs = (quad ^ (m16 & 3)) * 8;
        half8 af[4], bf[2];
        #pragma unroll
        for (int i = 0; i < 4; ++i) af[i] = *(half8*)&As[(wm*64 + i*16 + m16)*32 + cs];
        #pragma unroll
        for (int j = 0; j < 2; ++j) bf[j] = *(half8*)&Bs[(wn*32 + j*16 + m16)*32 + cs];
        #pragma unroll
        for (int i = 0; i < 4; ++i)
            #pragma unroll
            for (int j = 0; j < 2; ++j)
                acc[i][j] = mfma16(af[i], bf[j], acc[i][j]);
        __syncthreads();
    }
    #pragma unroll
    for (int j = 0; j < 2; ++j) {
        int col = gn0 + wn*32 + j*16 + m16;
        int h = col >> 6, d = col & 63;
        float bb = bias ? bias[col] : 0.0f;
        #pragma unroll
        for (int i = 0; i < 4; ++i) {
            int r0 = gm0 + wm*64 + i*16 + quad*4;
            #pragma unroll
            for (int r = 0; r < 4; ++r) {
                float v = (acc[i][j][r] + bb) * scale;
                int m = r0 + r;
                int s = m >> 1, b = m & 1;
                if (mode == 2)
                    ((float*)out)[(size_t)m*EE + col] = v;
                else if (mode == 1)
                    ((f16*)out)[((((size_t)b*HH + h)*(SQ/32) + (s >> 5))*DD + d)*32 + (s & 31)] = (f16)v;
                else
                    ((f16*)out)[qk_frag((size_t)b*HH + h, s, d)] = (f16)v;
            }
        }
    }
}

__global__ __launch_bounds__(256) void k_gemm_qkv(
    const f16* xq, const f16* qw, const float* qb,
    const f16* xk, const f16* kw, const float* kb,
    const f16* xv, const f16* vw, const float* vb,
    f16* Q16, f16* K16, f16* Vt16)
{
    int z = blockIdx.z;
    const f16* A = (z==0) ? xq : (z==1) ? xk : xv;
    const f16* W = (z==0) ? qw : (z==1) ? kw : vw;
    const float* bi = (z==0) ? qb : (z==1) ? kb : vb;
    float sc = (z==0) ? 0.125f * LOG2E : 1.0f;   // fold log2e into Q
    void* o = (z==0) ? (void*)Q16 : (z==1) ? (void*)K16 : (void*)Vt16;
    gemm_body(A, W, bi, sc, o, (z==2) ? 1 : 0);
}

__global__ __launch_bounds__(256) void k_gemm_o(const f16* A, const f16* W, float* out)
{
    gemm_body(A, W, nullptr, 1.0f, out, 2);
}

// ---------------- phase 1: lse2[b,h,q] = log2(sum_k 2^s2) ----------------
// Frag-tiled Q/K: every fragment load is a contiguous 1KB wave transaction.
// q-tile 128 (halves K re-read volume vs 64). Flat 512-wg grid, XCD-swizzled
// by (h,b) combo (c&7 == XCD).
__global__ __launch_bounds__(256, 4) void k_attn_l(
    const f16* __restrict__ Q16, const f16* __restrict__ K16, float* __restrict__ lse2)
{
    __shared__ float red[4][128];
    const int t = threadIdx.x, lane = t & 63, w = t >> 6;
    const int quad = lane >> 4, m16 = lane & 15;
    const int bid = blockIdx.x;
    const int xcd = bid & 7, idx = bid >> 3;     // idx in [0,64)
    const int c = ((idx & 3) << 3) + xcd;        // (h,b) combo, c&7 == xcd
    const int q0 = (idx >> 2) * 128;             // q-tile in [0,16)*128
    const int h = c >> 1, b = c & 1;
    const size_t bh = (size_t)b*HH + h;
    const f16* Qf = Q16 + bh*SQ*DD;
    const f16* Kf = K16 + bh*SQ*DD;

    half8 bq[8][2];
    #pragma unroll
    for (int nt = 0; nt < 8; ++nt)
        #pragma unroll
        for (int dk = 0; dk < 2; ++dk)
            bq[nt][dk] = *(const half8*)&Qf[(((size_t)(q0 >> 4) + nt)*2 + dk)*512 + m16*32 + quad*8];

    float lsum[8] = {};
    for (int kt = 0; kt < 16; ++kt) {
        half8 ak[2][2];
        #pragma unroll
        for (int mt = 0; mt < 2; ++mt)
            #pragma unroll
            for (int dk = 0; dk < 2; ++dk)
                ak[mt][dk] = *(const half8*)&Kf[(((size_t)kt*8 + w*2 + mt)*2 + dk)*512 + m16*32 + quad*8];
        #pragma unroll
        for (int mt = 0; mt < 2; ++mt)
            #pragma unroll
            for (int nt = 0; nt < 8; ++nt) {
                f32x4 s = {};
                s = mfma16(ak[mt][0], bq[nt][0], s);   // S^T: rows k, cols q
                s = mfma16(ak[mt][1], bq[nt][1], s);
                lsum[nt] += __builtin_amdgcn_exp2f(s[0]) + __builtin_amdgcn_exp2f(s[1])
                          + __builtin_amdgcn_exp2f(s[2]) + __builtin_amdgcn_exp2f(s[3]);
            }
    }
    #pragma unroll
    for (int nt = 0; nt < 8; ++nt) {
        float v = lsum[nt];
        v += __shfl_xor(v, 16, 64);
        v += __shfl_xor(v, 32, 64);
        lsum[nt] = v;
    }
    if (quad == 0)
        #pragma unroll
        for (int nt = 0; nt < 8; ++nt) red[w][nt*16 + m16] = lsum[nt];
    __syncthreads();
    if (t < 128) {
        float v = red[0][t] + red[1][t] + red[2][t] + red[3][t];
        lse2[bh*SQ + q0 + t] = __log2f(v);
    }
}

// ---------------- phase 2: probs, avg_attn (regs), ctx partials ----------------
// q-tile 128, KSLICE 128 (NSLICE 16): K/V re-read volume 4x lower than q-tile 32.
// Flat 512-wg grid, XCD-swizzled by (sl,b) combo. One kt-round per head:
// K/V frags direct from global (contiguous 1KB transactions), QK->exp->ps (LDS),
// barrier, PV from ps, ctx partial stored f16 per head. 2 barriers/head = 32 total.
__global__ __launch_bounds__(256, 2) void k_attn_main(
    const f16* __restrict__ Q16, const f16* __restrict__ K16, const f16* __restrict__ Vt16,
    const float* __restrict__ lse2, f16* __restrict__ ctxp, float* __restrict__ avg_out)
{
    __shared__ f16 ps[128][136];     // S^T tile: [q][k], 272B rows (16B-aligned)
    __shared__ float csh[HH][QT];
    const int t = threadIdx.x, lane = t & 63, w = t >> 6;
    const int quad = lane >> 4, m16 = lane & 15;
    const int bid = blockIdx.x;
    const int xcd = bid & 7, idx = bid >> 3;
    const int c = ((idx & 3) << 3) + xcd;        // (sl,b) combo, c&7 == xcd
    const int q0 = (idx >> 2) * QT;              // q-tile in [0,16)*128
    const int sl = c >> 1, b = c & 1;
    const int ks0 = sl * KSLICE;

    for (int i = t; i < HH*QT; i += 256)
        csh[i >> 7][i & 127] = lse2[((size_t)b*HH + (i >> 7))*SQ + q0 + (i & 127)];
    __syncthreads();

    float avg_r[8][8] = {};   // [nt][mt*4+r]: lane-exclusive (q,k) slots over h

    for (int h = 0; h < HH; ++h) {
        const size_t bh = (size_t)b*HH + h;
        const f16* Qf = Q16 + bh*SQ*DD;
        const f16* Kf = K16 + bh*SQ*DD;
        const f16* Vh = Vt16 + bh*SQ*DD;

        // wave-exclusive K frags (32 k) and V frags (d-block w, all 128 k)
        half8 ak[2][2];
        #pragma unroll
        for (int mt = 0; mt < 2; ++mt)
            #pragma unroll
            for (int dk = 0; dk < 2; ++dk)
                ak[mt][dk] = *(const half8*)&Kf[(((size_t)(ks0 >> 4) + w*2 + mt)*2 + dk)*512 + m16*32 + quad*8];
        half8 bv[4];
        #pragma unroll
        for (int ks = 0; ks < 4; ++ks)
            bv[ks] = *(const half8*)&Vh[(((size_t)(ks0 >> 5) + ks)*DD + w*16 + m16)*32 + quad*8];

        // QK phase: nt-pipelined bq loads (double-buffered, parity static via unroll)
        half8 bqA[2], bqB[2];
        #pragma unroll
        for (int dk = 0; dk < 2; ++dk)
            bqA[dk] = *(const half8*)&Qf[(((size_t)(q0 >> 4) + 0)*2 + dk)*512 + m16*32 + quad*8];
        #pragma unroll
        for (int nt = 0; nt < 8; ++nt) {
            if (nt + 1 < 8) {
                if (nt & 1) {
                    #pragma unroll
                    for (int dk = 0; dk < 2; ++dk)
                        bqA[dk] = *(const half8*)&Qf[(((size_t)(q0 >> 4) + nt + 1)*2 + dk)*512 + m16*32 + quad*8];
                } else {
                    #pragma unroll
                    for (int dk = 0; dk < 2; ++dk)
                        bqB[dk] = *(const half8*)&Qf[(((size_t)(q0 >> 4) + nt + 1)*2 + dk)*512 + m16*32 + quad*8];
                }
            }
            const float cc = csh[h][nt*16 + m16];
            #pragma unroll
            for (int mt = 0; mt < 2; ++mt) {
                f32x4 s = {};
                if (nt & 1) {
                    s = mfma16(ak[mt][0], bqB[0], s);
                    s = mfma16(ak[mt][1], bqB[1], s);
                } else {
                    s = mfma16(ak[mt][0], bqA[0], s);
                    s = mfma16(ak[mt][1], bqA[1], s);
                }
                half4 ph;
                #pragma unroll
                for (int r = 0; r < 4; ++r) {
                    float p = __builtin_amdgcn_exp2f(s[r] - cc);
                    avg_r[nt][mt*4 + r] += p;
                    ph[r] = (f16)p;
                }
                *(half4*)&ps[nt*16 + m16][w*32 + mt*16 + quad*4] = ph;
            }
        }
        // ps complete: LDS-order barrier, global prefetches stay in flight (T4)
        __builtin_amdgcn_sched_barrier(0);
        __builtin_amdgcn_s_waitcnt(0xC07F);   // lgkmcnt(0)
        __builtin_amdgcn_s_barrier();
        __builtin_amdgcn_sched_barrier(0);

        // PV: wave w owns d-block w*16; per qt transient accumulator -> f16 ctxp
        #pragma unroll
        for (int qt = 0; qt < 8; ++qt) {
            f32x4 cacc = {};
            #pragma unroll
            for (int ks = 0; ks < 4; ++ks) {
                half8 ap = *(half8*)&ps[qt*16 + m16][ks*32 + quad*8];
                cacc = mfma16(ap, bv[ks], cacc);
            }
            #pragma unroll
            for (int r = 0; r < 4; ++r) {
                int q = q0 + qt*16 + quad*4 + r;
                ctxp[(size_t)sl*MM*EE + ((size_t)q*BB + b)*EE + h*DD + w*16 + m16] = (f16)cacc[r];
            }
        }
        // all ps reads done before next head overwrites
        __builtin_amdgcn_sched_barrier(0);
        __builtin_amdgcn_s_waitcnt(0xC07F);   // lgkmcnt(0)
        __builtin_amdgcn_s_barrier();
        __builtin_amdgcn_sched_barrier(0);
    }

    // write owned avg tile (float4 stores)
    #pragma unroll
    for (int nt = 0; nt < 8; ++nt)
        #pragma unroll
        for (int mt = 0; mt < 2; ++mt) {
            int q = q0 + nt*16 + m16;
            int k = ks0 + w*32 + mt*16 + quad*4;
            float4 v = { avg_r[nt][mt*4+0]*(1.0f/HH), avg_r[nt][mt*4+1]*(1.0f/HH),
                         avg_r[nt][mt*4+2]*(1.0f/HH), avg_r[nt][mt*4+3]*(1.0f/HH) };
            *(float4*)&avg_out[((size_t)b*SQ + q)*SQ + k] = v;
        }
}

// ---------------- ctx partial reduction: f16 x NSLICE -> f16 ----------------
__global__ void k_ctx_red(const f16* __restrict__ ctxp, f16* __restrict__ ctx16) {
    size_t i = ((size_t)blockIdx.x * 256 + threadIdx.x) * 8;
    float s[8] = {};
    #pragma unroll
    for (int sl = 0; sl < NSLICE; ++sl) {
        half8 v = *(const half8*)&ctxp[(size_t)sl*MM*EE + i];
        #pragma unroll
        for (int j = 0; j < 8; ++j) s[j] += (float)v[j];
    }
    half8 o;
    #pragma unroll
    for (int j = 0; j < 8; ++j) o[j] = (f16)s[j];
    *(half8*)&ctx16[i] = o;
}

// ---------------- launch ----------------
extern "C" void kernel_launch(void* const* d_in, const int* in_sizes, int n_in,
                              void* d_out, int out_size, void* d_ws, size_t ws_size,
                              hipStream_t stream) {
    const float* query    = (const float*)d_in[0];
    const float* key      = (const float*)d_in[1];
    const float* value    = (const float*)d_in[2];
    const float* q_w      = (const float*)d_in[3];
    const float* q_b      = (const float*)d_in[4];
    const float* k_w      = (const float*)d_in[5];
    const float* k_b      = (const float*)d_in[6];
    const float* v_w      = (const float*)d_in[7];
    const float* v_b      = (const float*)d_in[8];
    const float* o_w_mean = (const float*)d_in[9];
    const float* o_w_lgstd= (const float*)d_in[10];
    const float* eps      = (const float*)d_in[11];
    float* out = (float*)d_out;                  // [S,B,E] fp32
    float* avg = out + (size_t)MM * EE;          // [B,S,S] fp32

    const size_t EWN = (size_t)EE*EE;   // 1M
    const size_t XWN = (size_t)MM*EE;   // 4M
    f16* qw16  = (f16*)d_ws;
    f16* kw16  = qw16 + EWN;
    f16* vw16  = kw16 + EWN;
    f16* ow16  = vw16 + EWN;
    f16* Q16   = ow16 + EWN;
    f16* K16   = Q16  + XWN;
    f16* Vt16  = K16  + XWN;
    f16* ctx16 = Vt16 + XWN;
    float* lse2 = (float*)(ctx16 + XWN);             // B*H*S fp32
    f16* xq16  = (f16*)(lse2 + (size_t)BB*HH*SQ);
    f16* xk16  = xq16 + XWN;
    f16* xv16  = xk16 + XWN;
    // ctxp (f16, NSLICE slices) aliases xq/xk/xv (dead after projections) and
    // extends beyond: NSLICE * 8MB = 128MB. Total ws footprint ~170MB.
    f16* ctxp = xq16;

    k_elem<<<dim3(XWN/1024, 7), 256, 0, stream>>>(q_w, k_w, v_w, query, key, value,
        o_w_mean, o_w_lgstd, eps, qw16, kw16, vw16, xq16, xk16, xv16, ow16);

    k_gemm_qkv<<<dim3(MM/128, EE/64, 3), 256, 0, stream>>>(
        xq16, qw16, q_b, xk16, kw16, k_b, xv16, vw16, v_b, Q16, K16, Vt16);

    k_attn_l   <<<dim3((SQ/128) * HH * BB), 256, 0, stream>>>(Q16, K16, lse2);
    k_attn_main<<<dim3((SQ/QT) * NSLICE * BB), 256, 0, stream>>>(Q16, K16, Vt16, lse2, ctxp, avg);
    k_ctx_red  <<<XWN/2048, 256, 0, stream>>>(ctxp, ctx16);

    k_gemm_o<<<dim3(MM/128, EE/64), 256, 0, stream>>>(ctx16, ow16, out);
}